// Round 1
// 218.333 us; speedup vs baseline: 1.0157x; 1.0157x over previous
//
#include <hip/hip_runtime.h>
#include <math.h>

constexpr int KK = 2;
constexpr int HH = 4;
constexpr int NN = 4096;
constexpr int DD = 64;
constexpr int OO = 64;
constexpr int NU = 4000;
constexpr int CC = 2;
constexpr int JSPLIT = 16;
constexpr int JCHUNK = NN / JSPLIT;  // 256
constexpr float LOG2E = 1.44269504088896340736f;

typedef float vf4 __attribute__((ext_vector_type(4)));
typedef float vf2 __attribute__((ext_vector_type(2)));

__device__ __forceinline__ float fexp2(float x) {
#if __has_builtin(__builtin_amdgcn_exp2f)
  return __builtin_amdgcn_exp2f(x);
#else
  return exp2f(x);
#endif
}
__device__ __forceinline__ float frcp(float x) {
#if __has_builtin(__builtin_amdgcn_rcpf)
  return __builtin_amdgcn_rcpf(x);
#else
  return 1.0f / x;
#endif
}
__device__ __forceinline__ float ftanh(float x) {
  float e = fexp2(x * (2.0f * LOG2E));
  return 1.0f - 2.0f * frcp(e + 1.0f);
}

// ---------------------------------------------------------------------------
// Phase 1: per (k,h): hp = h @ w (4096x64 @ 64x64); per node n, PLANAR outputs:
//   Ap [kh][n] = 2^src'      A5p[kh][n] = 2^(0.2 src')   (src' = tanh-dot * log2e)
//   Bp [kh][n] = 2^dst'      B5p[kh][n] = 2^(0.2 dst')
//   G0p[kh][n] = hp_n.fc_w0  G1p[kh][n] = hp_n.fc_w1
// Factorized leaky-softmax: exp2(max(s,0.2s)) = max(A*B, A5*B5).
// grid (64, K*H), block 256. Thread = 4 rows x 4 o tile; LDS transpose epi.
// Epilogue val = tid>>6 (wave-uniform branch, no intra-wave divergence).
// ---------------------------------------------------------------------------
__global__ __launch_bounds__(256) void gat_phase1(
    const float* __restrict__ hsrc, const float* __restrict__ w,
    const float* __restrict__ a_src, const float* __restrict__ a_dst,
    const float* __restrict__ fc_w,
    float* __restrict__ Ap, float* __restrict__ A5p,
    float* __restrict__ Bp, float* __restrict__ B5p,
    float* __restrict__ G0p, float* __restrict__ G1p) {
  const int kh = blockIdx.y;  // 0..7
  const int k = kh >> 2;
  const int i0 = blockIdx.x * 64;
  const int tid = threadIdx.x;

  __shared__ float h_s[DD][68];
  __shared__ float w_s[DD][OO];
  __shared__ float part[4][64][17];  // [val][row][og], padded

  {
    const vf4* wp = (const vf4*)(w + (size_t)kh * DD * OO);
    vf4* ws4 = (vf4*)w_s;
    for (int t = tid; t < DD * OO / 4; t += 256) ws4[t] = wp[t];
  }
  for (int t = tid; t < 1024; t += 256) {
    const int row = t >> 4;
    const int f4 = (t & 15) * 4;
    vf4 v = *(const vf4*)(hsrc + (size_t)(i0 + row) * DD + f4);
    h_s[f4 + 0][row] = v.x;
    h_s[f4 + 1][row] = v.y;
    h_s[f4 + 2][row] = v.z;
    h_s[f4 + 3][row] = v.w;
  }
  __syncthreads();

  const int og = tid & 15;
  const int rg = tid >> 4;
  const int o0 = og * 4;
  const int r0 = rg * 4;

  float hp[4][4];
#pragma unroll
  for (int j = 0; j < 4; ++j)
#pragma unroll
    for (int u = 0; u < 4; ++u) hp[j][u] = 0.0f;

#pragma unroll 8
  for (int f = 0; f < DD; ++f) {
    vf4 hv = *(const vf4*)&h_s[f][r0];
    vf4 wv = *(const vf4*)&w_s[f][o0];
    hp[0][0] = fmaf(hv.x, wv.x, hp[0][0]);
    hp[0][1] = fmaf(hv.x, wv.y, hp[0][1]);
    hp[0][2] = fmaf(hv.x, wv.z, hp[0][2]);
    hp[0][3] = fmaf(hv.x, wv.w, hp[0][3]);
    hp[1][0] = fmaf(hv.y, wv.x, hp[1][0]);
    hp[1][1] = fmaf(hv.y, wv.y, hp[1][1]);
    hp[1][2] = fmaf(hv.y, wv.z, hp[1][2]);
    hp[1][3] = fmaf(hv.y, wv.w, hp[1][3]);
    hp[2][0] = fmaf(hv.z, wv.x, hp[2][0]);
    hp[2][1] = fmaf(hv.z, wv.y, hp[2][1]);
    hp[2][2] = fmaf(hv.z, wv.z, hp[2][2]);
    hp[2][3] = fmaf(hv.z, wv.w, hp[2][3]);
    hp[3][0] = fmaf(hv.w, wv.x, hp[3][0]);
    hp[3][1] = fmaf(hv.w, wv.y, hp[3][1]);
    hp[3][2] = fmaf(hv.w, wv.z, hp[3][2]);
    hp[3][3] = fmaf(hv.w, wv.w, hp[3][3]);
  }

  float as[4], ad[4], f0[4], f1[4];
#pragma unroll
  for (int u = 0; u < 4; ++u) {
    as[u] = a_src[kh * OO + o0 + u];
    ad[u] = a_dst[kh * OO + o0 + u];
    f0[u] = fc_w[0 * (KK * OO) + k * OO + o0 + u];
    f1[u] = fc_w[1 * (KK * OO) + k * OO + o0 + u];
  }

#pragma unroll
  for (int j = 0; j < 4; ++j) {
    float sp = 0.0f, dp = 0.0f, g0 = 0.0f, g1 = 0.0f;
#pragma unroll
    for (int u = 0; u < 4; ++u) {
      float v = hp[j][u];
      float t = ftanh(v);
      sp = fmaf(t, as[u], sp);
      dp = fmaf(t, ad[u], dp);
      g0 = fmaf(v, f0[u], g0);
      g1 = fmaf(v, f1[u], g1);
    }
    part[0][r0 + j][og] = sp;
    part[1][r0 + j][og] = dp;
    part[2][r0 + j][og] = g0;
    part[3][r0 + j][og] = g1;
  }
  __syncthreads();

  {  // wave = val plane (uniform branch), lane = row j2; sum 16 og-partials
    const int val = tid >> 6;
    const int j2 = tid & 63;
    const float* pr = &part[val][j2][0];
    vf4 s0 = *(const vf4*)(pr + 0);
    vf4 s1 = *(const vf4*)(pr + 4);
    vf4 s2 = *(const vf4*)(pr + 8);
    vf4 s3 = *(const vf4*)(pr + 12);
    vf4 t4 = s0 + s1 + s2 + s3;
    float sum = t4.x + t4.y + t4.z + t4.w;
    const size_t idx = (size_t)kh * NN + i0 + j2;
    if (val == 0) {
      float sp = sum * LOG2E;
      Ap[idx] = fexp2(sp);
      A5p[idx] = fexp2(0.2f * sp);
    } else if (val == 1) {
      float dp = sum * LOG2E;
      Bp[idx] = fexp2(dp);
      B5p[idx] = fexp2(0.2f * dp);
    } else if (val == 2) {
      G0p[idx] = sum;
    } else {
      G1p[idx] = sum;
    }
  }
}

// ---------------------------------------------------------------------------
// Phase 2: partial softmax sums over a 256-j chunk, 16 rows per block.
// grid (NU/16, K*JSPLIT), block 256 = 4 waves. Lane = (jsub<<4) | row.
// Planar LDS planes {B,B5,G0,G1} enable packed-f32 (v_pk_*) inner loop:
//   e = max(A*B, A5*B5)  [== exp2(leaky(s)), exact identity]
//   pa = adj*e; l += pa; a_c += pa*g_c     — all on vf2 j-pairs.
// 16 core VALU per (4j,h) vs 24 in the interleaved layout.
// ---------------------------------------------------------------------------
__global__ __launch_bounds__(256) void gat_phase2(
    const float* __restrict__ adj, const float* __restrict__ Ap,
    const float* __restrict__ A5p, const float* __restrict__ Bp,
    const float* __restrict__ B5p, const float* __restrict__ G0p,
    const float* __restrict__ G1p, float* __restrict__ P) {
  const int k = blockIdx.y >> 4;
  const int chunk = blockIdx.y & 15;
  const int r0 = blockIdx.x * 16;
  const int tid = threadIdx.x;
  const int wave = tid >> 6;
  const int lane = tid & 63;
  const int row = lane & 15;
  const int jsub = lane >> 4;
  const int i = r0 + row;
  const int j0 = chunk * JCHUNK;

  __shared__ float lds[4][HH][JCHUNK];  // B,B5,G0,G1 planes: 16 KB

  {  // stage: step = plane; thread -> (h = tid>>6, 16B pos), fully coalesced
    const float* plane_src[4] = {Bp, B5p, G0p, G1p};
    const int h = tid >> 6;
    const int pos = (tid & 63) * 4;
    const size_t gbase = (size_t)(k * HH + h) * NN + j0 + pos;
#pragma unroll
    for (int step = 0; step < 4; ++step) {
      vf4 v = *(const vf4*)(plane_src[step] + gbase);
      *(vf4*)&lds[step][h][pos] = v;
    }
  }

  vf2 Apk[4], A5pk[4];
#pragma unroll
  for (int h = 0; h < 4; ++h) {
    const size_t ia = (size_t)(k * HH + h) * NN + i;
    float a = Ap[ia];
    float a5 = A5p[ia];
    Apk[h] = (vf2){a, a};
    A5pk[h] = (vf2){a5, a5};
  }

  vf2 l2[4], a02[4], a12[4];
#pragma unroll
  for (int h = 0; h < 4; ++h) {
    l2[h] = (vf2){0.0f, 0.0f};
    a02[h] = (vf2){0.0f, 0.0f};
    a12[h] = (vf2){0.0f, 0.0f};
  }

  __syncthreads();

  // 16 tiles of 16 j; wave handles t = wave + s*4, s=0..3, all prefetched.
  const float* arow =
      adj + (size_t)k * NN * NN + (size_t)i * NN + j0 + jsub * 4;
  vf4 aj[4];
#pragma unroll
  for (int q = 0; q < 4; ++q)
    aj[q] = *(const vf4*)(arow + (wave + q * 4) * 16);

#pragma unroll
  for (int s = 0; s < 4; ++s) {
    const int t = wave + s * 4;
    const vf4 av = aj[s];
    const vf2 av01 = (vf2){av.x, av.y};
    const vf2 av23 = (vf2){av.z, av.w};
    const int jl = t * 16 + jsub * 4;
#pragma unroll
    for (int h = 0; h < 4; ++h) {
      vf4 Bv = *(const vf4*)&lds[0][h][jl];
      vf4 B5v = *(const vf4*)&lds[1][h][jl];
      vf4 G0v = *(const vf4*)&lds[2][h][jl];
      vf4 G1v = *(const vf4*)&lds[3][h][jl];

      vf2 m01 = Apk[h] * (vf2){Bv.x, Bv.y};    // v_pk_mul_f32
      vf2 n01 = A5pk[h] * (vf2){B5v.x, B5v.y};
      vf2 e01 = (vf2){fmaxf(m01.x, n01.x), fmaxf(m01.y, n01.y)};
      vf2 pa01 = e01 * av01;
      l2[h] += pa01;                            // v_pk_add_f32
      a02[h] += pa01 * (vf2){G0v.x, G0v.y};     // v_pk_fma_f32
      a12[h] += pa01 * (vf2){G1v.x, G1v.y};

      vf2 m23 = Apk[h] * (vf2){Bv.z, Bv.w};
      vf2 n23 = A5pk[h] * (vf2){B5v.z, B5v.w};
      vf2 e23 = (vf2){fmaxf(m23.x, n23.x), fmaxf(m23.y, n23.y)};
      vf2 pa23 = e23 * av23;
      l2[h] += pa23;
      a02[h] += pa23 * (vf2){G0v.z, G0v.w};
      a12[h] += pa23 * (vf2){G1v.z, G1v.w};
    }
  }

  // horizontal j-pair collapse, then butterfly over jsub (lane bits 4,5)
  float l[4], a0[4], a1[4];
#pragma unroll
  for (int h = 0; h < 4; ++h) {
    l[h] = l2[h].x + l2[h].y;
    a0[h] = a02[h].x + a02[h].y;
    a1[h] = a12[h].x + a12[h].y;
  }
#pragma unroll
  for (int h = 0; h < 4; ++h) {
    l[h] += __shfl_xor(l[h], 16, 64);
    l[h] += __shfl_xor(l[h], 32, 64);
    a0[h] += __shfl_xor(a0[h], 16, 64);
    a0[h] += __shfl_xor(a0[h], 32, 64);
    a1[h] += __shfl_xor(a1[h], 16, 64);
    a1[h] += __shfl_xor(a1[h], 32, 64);
  }

  // cross-wave combine: sred[wave][v][row], v = h*3+c
  __shared__ float sred[4][12][16];
  if (lane < 16) {
#pragma unroll
    for (int h = 0; h < 4; ++h) {
      sred[wave][h * 3 + 0][row] = l[h];
      sred[wave][h * 3 + 1][row] = a0[h];
      sred[wave][h * 3 + 2][row] = a1[h];
    }
  }
  __syncthreads();
  if (tid < 192) {
    const int v = tid >> 4;  // 0..11 = h*3+c
    const int rr = tid & 15;
    float sum =
        sred[0][v][rr] + sred[1][v][rr] + sred[2][v][rr] + sred[3][v][rr];
    const int h = v / 3, c = v % 3;
    // P layout: [k][chunk][h][{l,a0,a1}][i]
    size_t base =
        ((((size_t)(k * JSPLIT + chunk) * HH + h) * 3 + c)) * NU + (r0 + rr);
    P[base] = sum;
  }
}

// ---------------------------------------------------------------------------
// Phase 3: combine chunk partials, divide, mean heads, sum kinds, +bias,
// log_softmax over C=2. 8 lanes per row (one per (k,h)), shfl_xor reduce.
// grid 125 blocks (was 16) -> no longer single-digit-CU latency-bound.
// ---------------------------------------------------------------------------
__global__ __launch_bounds__(256) void gat_phase3(
    const float* __restrict__ P, const float* __restrict__ fc_b,
    float* __restrict__ out) {
  const int tid = threadIdx.x;
  const int g = tid & 7;    // kh pair index
  const int il = tid >> 3;  // 0..31
  const int i = blockIdx.x * 32 + il;  // 125*32 == NU exactly
  const int k = g >> 2, h = g & 3;

  float ls = 0.0f, a0 = 0.0f, a1 = 0.0f;
#pragma unroll
  for (int ch = 0; ch < JSPLIT; ++ch) {
    size_t b = (((size_t)(k * JSPLIT + ch) * HH + h) * 3) * NU + i;
    ls += P[b];
    a0 += P[b + NU];
    a1 += P[b + 2 * (size_t)NU];
  }
  float inv = 1.0f / ls;
  float p0 = 0.25f * a0 * inv;
  float p1 = 0.25f * a1 * inv;

  p0 += __shfl_xor(p0, 1, 64);
  p0 += __shfl_xor(p0, 2, 64);
  p0 += __shfl_xor(p0, 4, 64);
  p1 += __shfl_xor(p1, 1, 64);
  p1 += __shfl_xor(p1, 2, 64);
  p1 += __shfl_xor(p1, 4, 64);

  if (g == 0) {
    float l0 = p0 + fc_b[0];
    float l1 = p1 + fc_b[1];
    float m = fmaxf(l0, l1);
    float lse = m + logf(expf(l0 - m) + expf(l1 - m));
    out[(size_t)i * CC + 0] = l0 - lse;
    out[(size_t)i * CC + 1] = l1 - lse;
  }
}

extern "C" void kernel_launch(void* const* d_in, const int* in_sizes, int n_in,
                              void* d_out, int out_size, void* d_ws, size_t ws_size,
                              hipStream_t stream) {
  const float* hsrc  = (const float*)d_in[0];  // (1,4096,64)
  const float* hadj  = (const float*)d_in[1];  // (2,1,4096,4096)
  const float* w     = (const float*)d_in[2];  // (2,4,64,64)
  const float* a_src = (const float*)d_in[3];  // (2,4,64,1)
  const float* a_dst = (const float*)d_in[4];  // (2,4,64,1)
  const float* fc_w  = (const float*)d_in[5];  // (2,128)
  const float* fc_b  = (const float*)d_in[6];  // (2,)
  float* out = (float*)d_out;                  // (1,4000,2) fp32

  char* ws = (char*)d_ws;
  // planar KH*NN planes, 128 KB each
  float* Ap  = (float*)(ws + 0);
  float* A5p = (float*)(ws + 131072);
  float* Bp  = (float*)(ws + 262144);
  float* B5p = (float*)(ws + 393216);
  float* G0p = (float*)(ws + 524288);
  float* G1p = (float*)(ws + 655360);
  float* P   = (float*)(ws + 786432);  // K*JSPLIT*H*3*NU floats (~6.1 MB)

  dim3 g1(NN / 64, KK * HH);
  gat_phase1<<<g1, 256, 0, stream>>>(hsrc, w, a_src, a_dst, fc_w,
                                     Ap, A5p, Bp, B5p, G0p, G1p);
  dim3 g2(NU / 16, KK * JSPLIT);
  gat_phase2<<<g2, 256, 0, stream>>>(hadj, Ap, A5p, Bp, B5p, G0p, G1p, P);
  gat_phase3<<<NU / 32, 256, 0, stream>>>(P, fc_b, out);
}